// Round 3
// baseline (73.116 us; speedup 1.0000x reference)
//
#include <hip/hip_runtime.h>

#define NBLK 1024
#define NTHR 256
#define LAMBDA_PT 0.1f

// Kernel 1: per-block partial sums.
//   ws[0 .. NBLK-1]        : block partial of sum((y-x)^2)
//   ws[NBLK .. 2*NBLK-1]   : block partial of sum_b s4_b / (s2_b)^2  (one z-row per wave)
__global__ __launch_bounds__(NTHR) void ebgan_partial(
    const float4* __restrict__ y, const float4* __restrict__ x,
    const float4* __restrict__ z, float* __restrict__ ws,
    int n4, int b)
{
    const int tid = threadIdx.x;
    const int gid = blockIdx.x * NTHR + tid;

    // ---- MSE partial (grid-stride, float4) ----
    float mse = 0.f;
    for (int i = gid; i < n4; i += NBLK * NTHR) {
        float4 a = y[i];
        float4 c = x[i];
        float dx = a.x - c.x, dy = a.y - c.y, dz = a.z - c.z, dw = a.w - c.w;
        mse = fmaf(dx, dx, mse);
        mse = fmaf(dy, dy, mse);
        mse = fmaf(dz, dz, mse);
        mse = fmaf(dw, dw, mse);
    }
    #pragma unroll
    for (int o = 32; o > 0; o >>= 1) mse += __shfl_down(mse, o);

    // ---- z-row term: one wave (64 lanes) per batch row, 512 floats/row ----
    const int wid  = tid >> 6;    // wave in block: 0..3
    const int lane = tid & 63;
    const int gw   = blockIdx.x * (NTHR / 64) + wid;  // global wave id == row id
    float ratio = 0.f;
    if (gw < b) {
        const float4* zr = z + (size_t)gw * 128;  // 512 floats = 128 float4
        float4 v0 = zr[lane];
        float4 v1 = zr[64 + lane];
        float q0 = v0.x * v0.x, q1 = v0.y * v0.y, q2 = v0.z * v0.z, q3 = v0.w * v0.w;
        float q4 = v1.x * v1.x, q5 = v1.y * v1.y, q6 = v1.z * v1.z, q7 = v1.w * v1.w;
        float s2 = q0 + q1 + q2 + q3 + q4 + q5 + q6 + q7;
        float s4 = q0*q0 + q1*q1 + q2*q2 + q3*q3 + q4*q4 + q5*q5 + q6*q6 + q7*q7;
        #pragma unroll
        for (int o = 32; o > 0; o >>= 1) {
            s2 += __shfl_down(s2, o);
            s4 += __shfl_down(s4, o);
        }
        if (lane == 0) ratio = s4 / (s2 * s2);
    }

    // ---- block reduce across the 4 waves, write partials ----
    __shared__ float smse[NTHR / 64];
    __shared__ float srat[NTHR / 64];
    if (lane == 0) { smse[wid] = mse; srat[wid] = ratio; }
    __syncthreads();
    if (tid == 0) {
        ws[blockIdx.x]        = smse[0] + smse[1] + smse[2] + smse[3];
        ws[NBLK + blockIdx.x] = srat[0] + srat[1] + srat[2] + srat[3];
    }
}

// Kernel 2: reduce the 2*NBLK partials, write the scalar loss.
__global__ __launch_bounds__(NTHR) void ebgan_final(
    const float* __restrict__ ws, float* __restrict__ out,
    float inv_n, float cos_scale, float bf)
{
    const int tid = threadIdx.x;
    float mse = 0.f, rat = 0.f;
    for (int i = tid; i < NBLK; i += NTHR) {
        mse += ws[i];
        rat += ws[NBLK + i];
    }
    #pragma unroll
    for (int o = 32; o > 0; o >>= 1) {
        mse += __shfl_down(mse, o);
        rat += __shfl_down(rat, o);
    }
    __shared__ float sm[NTHR / 64];
    __shared__ float sr[NTHR / 64];
    const int wid = tid >> 6, lane = tid & 63;
    if (lane == 0) { sm[wid] = mse; sr[wid] = rat; }
    __syncthreads();
    if (tid == 0) {
        float msum = sm[0] + sm[1] + sm[2] + sm[3];
        float rsum = sr[0] + sr[1] + sr[2] + sr[3];
        // sum over batch of off-diagonal squared-cosine = b - sum(ratio_b)
        float cos_sum = bf - rsum;
        out[0] = msum * inv_n + LAMBDA_PT * cos_sum * cos_scale;
    }
}

extern "C" void kernel_launch(void* const* d_in, const int* in_sizes, int n_in,
                              void* d_out, int out_size, void* d_ws, size_t ws_size,
                              hipStream_t stream) {
    const float4* y = (const float4*)d_in[0];   // yhat_xhat (256,3,64,64) f32
    const float4* x = (const float4*)d_in[1];   // xhat
    const float4* z = (const float4*)d_in[2];   // z_xhat (256,512) f32
    float* out = (float*)d_out;
    float* ws  = (float*)d_ws;

    const int n  = in_sizes[0];      // 3,145,728
    const int n4 = n / 4;
    const int h  = 512;
    const int b  = in_sizes[2] / h;  // 256

    ebgan_partial<<<NBLK, NTHR, 0, stream>>>(y, x, z, ws, n4, b);

    const float inv_n     = 1.0f / (float)n;
    const float cos_scale = 1.0f / ((float)b * (float)h * (float)h);
    ebgan_final<<<1, NTHR, 0, stream>>>(ws, out, inv_n, cos_scale, (float)b);
}